// Round 1
// baseline (659.317 us; speedup 1.0000x reference)
//
#include <hip/hip_runtime.h>
#include <hip/hip_bf16.h>

typedef float f32x4 __attribute__((ext_vector_type(4)));
typedef short s16x8 __attribute__((ext_vector_type(8)));
typedef short s16x4 __attribute__((ext_vector_type(4)));

#define THREADS 256

__device__ __forceinline__ unsigned short f2bf(float f) {
  union { float f; unsigned int u; } v;
  v.f = f;
  unsigned int u = v.u;
  u += 0x7fffu + ((u >> 16) & 1u);   // round-to-nearest-even (finite data only)
  return (unsigned short)(u >> 16);
}

struct GemmArgs {
  const float* W[4];
  const float* Bi[4];
};

// Y[e] = act(X[e] (64xK, bf16) @ W[e]^T (NxK, f32) + bias[e])
// Grid: (N/48, 4 experts). Block 256 = 4 waves; wave w owns output rows 16w..16w+15.
// W streamed f32 -> bf16 -> LDS (double-buffered, KC=256), XOR-swizzled vs 16-way
// bank conflicts on ds_read_b128 (row stride 512B aliases mod 128B -> G4 fix).
template<bool GELU, bool OUTBF16>
__global__ __launch_bounds__(THREADS) void mlp_gemm(
    const unsigned short* __restrict__ X, unsigned long long xstride,
    GemmArgs args,
    void* __restrict__ Y, unsigned long long ystride,
    int N, int K)
{
  constexpr int NT = 48;
  constexpr int KC = 256;
  __shared__ __align__(16) unsigned short Wb[2][NT * KC]; // 2 x 24 KB

  const int e    = blockIdx.y;
  const int n0   = blockIdx.x * NT;
  const int t    = threadIdx.x;
  const int lane = t & 63;
  const int wid  = t >> 6;

  const float* __restrict__ Wg = args.W[e];
  const unsigned short* __restrict__ Xg = X + (size_t)e * xstride;

  // staging: quad q = rd*256 + t ; row = q/64 (48 rows over 12 rounds), kq = q%64
  const int srow = t >> 6;   // + 4*rd
  const int skq  = t & 63;

  f32x4 sreg[12];

  auto load_stage = [&](int k0) {
#pragma unroll
    for (int rd = 0; rd < 12; ++rd) {
      const int row = rd * 4 + srow;
      sreg[rd] = *(const f32x4*)(Wg + (size_t)(n0 + row) * K + k0 + skq * 4);
    }
  };

  auto write_stage = [&](int bi) {
    unsigned short* lds = Wb[bi];
#pragma unroll
    for (int rd = 0; rd < 12; ++rd) {
      const int row = rd * 4 + srow;
      // element offset with 16B-chunk XOR swizzle: chunk' = chunk ^ (row&7)
      const int off = row * KC + ((((skq >> 1) ^ (row & 7)) << 3) | ((skq & 1) << 2));
      s16x4 p;
      p[0] = (short)f2bf(sreg[rd][0]);
      p[1] = (short)f2bf(sreg[rd][1]);
      p[2] = (short)f2bf(sreg[rd][2]);
      p[3] = (short)f2bf(sreg[rd][3]);
      *(s16x4*)(lds + off) = p;
    }
  };

  f32x4 acc[3];
#pragma unroll
  for (int i = 0; i < 3; ++i)
#pragma unroll
    for (int j = 0; j < 4; ++j) acc[i][j] = 0.0f;

  const int arow = wid * 16 + (lane & 15);
  const int kfr  = (lane >> 4) * 8;
  const unsigned short* __restrict__ xrow = Xg + (size_t)arow * K + kfr;
  const int brow0 = lane & 15;
  const int bch   = lane >> 4;

  auto compute = [&](int bi, int kg) {
    const unsigned short* lds = Wb[bi];
#pragma unroll
    for (int kk = 0; kk < KC; kk += 32) {
      s16x8 a = *(const s16x8*)(xrow + kg + kk);
#pragma unroll
      for (int nf = 0; nf < 3; ++nf) {
        const int row = nf * 16 + brow0;
        const int ch  = ((kk >> 3) + bch) ^ (row & 7);
        s16x8 b = *(const s16x8*)(lds + row * KC + ch * 8);
        acc[nf] = __builtin_amdgcn_mfma_f32_16x16x32_bf16(a, b, acc[nf], 0, 0, 0);
      }
    }
  };

  const int NCH = K / KC;

  load_stage(0);
  write_stage(0);
  __syncthreads();

  for (int c = 0; c < NCH; ++c) {
    if (c + 1 < NCH) load_stage((c + 1) * KC);   // next chunk in flight during compute
    compute(c & 1, c * KC);
    __syncthreads();
    if (c + 1 < NCH) {
      write_stage((c + 1) & 1);
      __syncthreads();
    }
  }

  // epilogue: D frag mapping col = lane&15, row = (lane>>4)*4 + reg  [m89-verified]
  const float* __restrict__ Bi = args.Bi[e];
  const int col   = lane & 15;
  const int rbase = wid * 16 + ((lane >> 4) << 2);
#pragma unroll
  for (int nf = 0; nf < 3; ++nf) {
    const int nn = n0 + nf * 16 + col;
    const float bv = Bi[nn];
#pragma unroll
    for (int r = 0; r < 4; ++r) {
      float yv = acc[nf][r] + bv;
      if (GELU) yv = 0.5f * yv * (1.0f + erff(yv * 0.70710678118654752f));
      const size_t oidx = (size_t)e * ystride + (size_t)(rbase + r) * N + nn;
      if (OUTBF16) ((unsigned short*)Y)[oidx] = f2bf(yv);
      else         ((float*)Y)[oidx] = yv;
    }
  }
}

__global__ __launch_bounds__(THREADS) void cvt_u_kernel(
    const float* __restrict__ u, unsigned short* __restrict__ ub)
{
  const int i = blockIdx.x * THREADS + threadIdx.x;
  ub[i] = f2bf(u[i]);
}

// out[b,i,j] = base[i,j] + sum_r v1[r,b,i] * v2[r,b,j]
// V points at the 2 experts of this n: v[r][b][0..1535]; v1 = [:D1], v2 = [D1:]
template<int D1, int D2>
__global__ __launch_bounds__(THREADS) void synth_kernel(
    const float* __restrict__ Wbase, const float* __restrict__ V,
    float* __restrict__ Out)
{
  constexpr int QPR = D2 / 4;          // quads per output row
  constexpr int RP  = THREADS / QPR;   // rows processed in parallel
  constexpr size_t S = (size_t)64 * 1536;
  const int b    = blockIdx.y;
  const int i0   = blockIdx.x * 32;
  const int isub = threadIdx.x / QPR;
  const int jq   = threadIdx.x % QPR;
  const float* __restrict__ vb = V + (size_t)b * 1536;
  const f32x4 v2a = *(const f32x4*)(vb + D1 + jq * 4);
  const f32x4 v2b = *(const f32x4*)(vb + S + D1 + jq * 4);
#pragma unroll
  for (int ii = isub; ii < 32; ii += RP) {
    const int i = i0 + ii;
    const float a0 = vb[i];
    const float a1 = vb[S + i];
    const f32x4 w = *(const f32x4*)(Wbase + (size_t)i * D2 + jq * 4);
    f32x4 o = w + a0 * v2a + a1 * v2b;
    *(f32x4*)(Out + ((size_t)b * D1 + i) * D2 + jq * 4) = o;
  }
}

extern "C" void kernel_launch(void* const* d_in, const int* in_sizes, int n_in,
                              void* d_out, int out_size, void* d_ws, size_t ws_size,
                              hipStream_t stream) {
  const int Hh = 3072, IND = 256, OD = 1536;

  const float* u0  = (const float*)d_in[0];
  const float* w1  = (const float*)d_in[1];
  const float* w2  = (const float*)d_in[2];
  const float* win[2] = {(const float*)d_in[3], (const float*)d_in[9]};
  const float* bin[2] = {(const float*)d_in[4], (const float*)d_in[10]};
  const float* hw [2] = {(const float*)d_in[5], (const float*)d_in[11]};
  const float* hb [2] = {(const float*)d_in[6], (const float*)d_in[12]};
  const float* wou[2] = {(const float*)d_in[7], (const float*)d_in[13]};
  const float* bou[2] = {(const float*)d_in[8], (const float*)d_in[14]};

  char* ws = (char*)d_ws;
  unsigned short* ub = (unsigned short*)ws;                          // 32 KB
  unsigned short* hA = (unsigned short*)(ws + (64 << 10));           // 1.5 MB
  unsigned short* hB = (unsigned short*)(ws + (64 << 10) + (2 << 20));
  float*          vv = (float*)(ws + (64 << 10) + (4 << 20));        // 1.5 MB

  cvt_u_kernel<<<64, THREADS, 0, stream>>>(u0, ub);

  GemmArgs ga;
  // layer-in: K=256, N=3072
  for (int e = 0; e < 4; ++e) {
    const int n = e >> 1, r = e & 1;
    ga.W[e]  = win[n] + (size_t)r * Hh * IND;
    ga.Bi[e] = bin[n] + (size_t)r * Hh;
  }
  mlp_gemm<true, true><<<dim3(Hh / 48, 4), THREADS, 0, stream>>>(
      ub, 0ull, ga, hA, (unsigned long long)64 * Hh, Hh, IND);

  // hidden layers: K=N=3072
  for (int l = 0; l < 2; ++l) {
    for (int e = 0; e < 4; ++e) {
      const int n = e >> 1, r = e & 1;
      ga.W[e]  = hw[n] + (size_t)(r * 2 + l) * Hh * Hh;
      ga.Bi[e] = hb[n] + (size_t)(r * 2 + l) * Hh;
    }
    const unsigned short* xin = (l == 0) ? hA : hB;
    unsigned short*      yout = (l == 0) ? hB : hA;
    mlp_gemm<true, true><<<dim3(Hh / 48, 4), THREADS, 0, stream>>>(
        xin, (unsigned long long)64 * Hh, ga, yout, (unsigned long long)64 * Hh, Hh, Hh);
  }

  // out layer: K=3072, N=1536, f32 out, no activation
  for (int e = 0; e < 4; ++e) {
    const int n = e >> 1, r = e & 1;
    ga.W[e]  = wou[n] + (size_t)r * OD * Hh;
    ga.Bi[e] = bou[n] + (size_t)r * OD;
  }
  mlp_gemm<false, false><<<dim3(OD / 48, 4), THREADS, 0, stream>>>(
      hA, (unsigned long long)64 * Hh, ga, vv, (unsigned long long)64 * OD, OD, Hh);

  float* out = (float*)d_out;
  synth_kernel<1024, 512><<<dim3(1024 / 32, 64), THREADS, 0, stream>>>(w1, vv, out);
  synth_kernel<512, 1024><<<dim3(512 / 32, 64), THREADS, 0, stream>>>(
      w2, vv + (size_t)2 * 64 * 1536, out + (size_t)64 * 1024 * 512);
}

// Round 5
// 653.459 us; speedup vs baseline: 1.0090x; 1.0090x over previous
//
#include <hip/hip_runtime.h>
#include <hip/hip_bf16.h>

typedef float f32x4 __attribute__((ext_vector_type(4)));
typedef short s16x8 __attribute__((ext_vector_type(8)));
typedef short s16x4 __attribute__((ext_vector_type(4)));

#define THREADS 256

__device__ __forceinline__ unsigned short f2bf(float f) {
  union { float f; unsigned int u; } v;
  v.f = f;
  unsigned int u = v.u;
  u += 0x7fffu + ((u >> 16) & 1u);   // round-to-nearest-even (finite data only)
  return (unsigned short)(u >> 16);
}

struct GemmArgs {
  const float* W[4];
  const float* Bi[4];
};

// Y[e] = act(X[e] (64xK, bf16) @ W[e]^T (NxK, f32) + bias[e])
// Grid: (N/16, 4 experts). Block 256 = 4 waves; wave w owns M-rows 16w..16w+15,
// all 16 N-cols of the block tile. 3 blocks/CU for hidden layers (768 blocks)
// -> 12 waves/CU so HBM streaming stays continuous across barrier drains.
// W streamed f32 -> bf16 -> LDS, 2-deep ping-pong register staging (sA/sB)
// with write-after-compute so the c+1 loads get ~1.5 iterations of latency
// slack (compiler emits counted vmcnt). XOR chunk-swizzle kills the 16-way
// ds_read_b128 bank conflict from the 512B row stride (G4).
template<bool GELU, bool OUTBF16>
__global__ __launch_bounds__(THREADS, 3) void mlp_gemm(
    const unsigned short* __restrict__ X, unsigned long long xstride,
    GemmArgs args,
    void* __restrict__ Y, unsigned long long ystride,
    int N, int K)
{
  constexpr int NT = 16;
  constexpr int KC = 256;
  __shared__ __align__(16) unsigned short Wb[2][NT * KC]; // 2 x 8 KB

  const int e    = blockIdx.y;
  const int n0   = blockIdx.x * NT;
  const int t    = threadIdx.x;
  const int lane = t & 63;
  const int wid  = t >> 6;

  const float* __restrict__ Wg = args.W[e];
  const unsigned short* __restrict__ Xg = X + (size_t)e * xstride;

  const int srow = wid;      // staging row group: row = rd*4 + srow
  const int skq  = lane;     // f32x4 quad within row

  auto load_st = [&](f32x4 (&s)[4], int k0) {
#pragma unroll
    for (int rd = 0; rd < 4; ++rd) {
      const int row = rd * 4 + srow;
      s[rd] = *(const f32x4*)(Wg + (size_t)(n0 + row) * K + k0 + skq * 4);
    }
  };

  auto write_st = [&](int bi, const f32x4 (&s)[4]) {
    unsigned short* lds = Wb[bi];
#pragma unroll
    for (int rd = 0; rd < 4; ++rd) {
      const int row = rd * 4 + srow;
      // element offset with 16B-chunk XOR swizzle: chunk' = chunk ^ (row&7)
      const int off = row * KC + ((((skq >> 1) ^ (row & 7)) << 3) | ((skq & 1) << 2));
      s16x4 p;
      p[0] = (short)f2bf(s[rd][0]);
      p[1] = (short)f2bf(s[rd][1]);
      p[2] = (short)f2bf(s[rd][2]);
      p[3] = (short)f2bf(s[rd][3]);
      *(s16x4*)(lds + off) = p;
    }
  };

  f32x4 acc = {0.f, 0.f, 0.f, 0.f};

  const int arow = wid * 16 + (lane & 15);
  const unsigned short* __restrict__ xrow = Xg + (size_t)arow * K + ((lane >> 4) << 3);
  const int brow = lane & 15;
  const int bch  = lane >> 4;

  auto compute = [&](int bi, int kg) {
    const unsigned short* lds = Wb[bi];
    s16x8 af[8];
#pragma unroll
    for (int i = 0; i < 8; ++i)
      af[i] = *(const s16x8*)(xrow + kg + i * 32);   // L2-resident X, max ILP
#pragma unroll
    for (int i = 0; i < 8; ++i) {
      const int ch = ((i << 2) + bch) ^ (brow & 7);
      s16x8 b = *(const s16x8*)(lds + brow * KC + ch * 8);
      acc = __builtin_amdgcn_mfma_f32_16x16x32_bf16(af[i], b, acc, 0, 0, 0);
    }
  };

  const int NCH = K / KC;

  f32x4 sA[4], sB[4];
  load_st(sA, 0);
  if (NCH > 1) load_st(sB, KC);
  write_st(0, sA);
  __syncthreads();

  for (int c = 0; c < NCH; ++c) {
    const bool even = !(c & 1);
    if (c + 2 < NCH) {                 // refill the stage freed last iteration
      if (even) load_st(sA, (c + 2) * KC);
      else      load_st(sB, (c + 2) * KC);
    }
    compute(c & 1, c * KC);
    if (c + 1 < NCH) {                 // stage c+1 into the idle LDS buffer
      if (even) write_st(1, sB);
      else      write_st(0, sA);
    }
    __syncthreads();
  }

  // epilogue: D frag mapping col = lane&15, row = (lane>>4)*4 + reg  [m89-verified]
  const float* __restrict__ Bi = args.Bi[e];
  const int col   = lane & 15;
  const int nn    = n0 + col;
  const int rbase = wid * 16 + ((lane >> 4) << 2);
  const float bv  = Bi[nn];
#pragma unroll
  for (int r = 0; r < 4; ++r) {
    float yv = acc[r] + bv;
    if (GELU) yv = 0.5f * yv * (1.0f + erff(yv * 0.70710678118654752f));
    const size_t oidx = (size_t)e * ystride + (size_t)(rbase + r) * N + nn;
    if (OUTBF16) ((unsigned short*)Y)[oidx] = f2bf(yv);
    else         ((float*)Y)[oidx] = yv;
  }
}

__global__ __launch_bounds__(THREADS) void cvt_u_kernel(
    const float* __restrict__ u, unsigned short* __restrict__ ub)
{
  const int i = blockIdx.x * THREADS + threadIdx.x;
  ub[i] = f2bf(u[i]);
}

// out[b,i,j] = base[i,j] + sum_r v1[r,b,i] * v2[r,b,j]
// V points at the 2 experts of this net: v[r][b][0..1535]; v1 = [:D1], v2 = [D1:]
template<int D1, int D2>
__global__ __launch_bounds__(THREADS) void synth_kernel(
    const float* __restrict__ Wbase, const float* __restrict__ V,
    float* __restrict__ Out)
{
  constexpr int QPR = D2 / 4;          // quads per output row
  constexpr int RP  = THREADS / QPR;   // rows processed in parallel
  constexpr size_t S = (size_t)64 * 1536;
  const int b    = blockIdx.y;
  const int i0   = blockIdx.x * 32;
  const int isub = threadIdx.x / QPR;
  const int jq   = threadIdx.x % QPR;
  const float* __restrict__ vb = V + (size_t)b * 1536;
  const f32x4 v2a = *(const f32x4*)(vb + D1 + jq * 4);
  const f32x4 v2b = *(const f32x4*)(vb + S + D1 + jq * 4);
#pragma unroll
  for (int ii = isub; ii < 32; ii += RP) {
    const int i = i0 + ii;
    const float a0 = vb[i];
    const float a1 = vb[S + i];
    const f32x4 w = *(const f32x4*)(Wbase + (size_t)i * D2 + jq * 4);
    f32x4 o = w + a0 * v2a + a1 * v2b;
    *(f32x4*)(Out + ((size_t)b * D1 + i) * D2 + jq * 4) = o;
  }
}

extern "C" void kernel_launch(void* const* d_in, const int* in_sizes, int n_in,
                              void* d_out, int out_size, void* d_ws, size_t ws_size,
                              hipStream_t stream) {
  const int Hh = 3072, IND = 256, OD = 1536;

  const float* u0  = (const float*)d_in[0];
  const float* w1  = (const float*)d_in[1];
  const float* w2  = (const float*)d_in[2];
  const float* win[2] = {(const float*)d_in[3], (const float*)d_in[9]};
  const float* bin[2] = {(const float*)d_in[4], (const float*)d_in[10]};
  const float* hw [2] = {(const float*)d_in[5], (const float*)d_in[11]};
  const float* hb [2] = {(const float*)d_in[6], (const float*)d_in[12]};
  const float* wou[2] = {(const float*)d_in[7], (const float*)d_in[13]};
  const float* bou[2] = {(const float*)d_in[8], (const float*)d_in[14]};

  char* ws = (char*)d_ws;
  unsigned short* ub = (unsigned short*)ws;                          // 32 KB
  unsigned short* hA = (unsigned short*)(ws + (64 << 10));           // 1.5 MB
  unsigned short* hB = (unsigned short*)(ws + (64 << 10) + (2 << 20));
  float*          vv = (float*)(ws + (64 << 10) + (4 << 20));        // 1.5 MB

  cvt_u_kernel<<<64, THREADS, 0, stream>>>(u0, ub);

  GemmArgs ga;
  // layer-in: K=256, N=3072
  for (int e = 0; e < 4; ++e) {
    const int n = e >> 1, r = e & 1;
    ga.W[e]  = win[n] + (size_t)r * Hh * IND;
    ga.Bi[e] = bin[n] + (size_t)r * Hh;
  }
  mlp_gemm<true, true><<<dim3(Hh / 16, 4), THREADS, 0, stream>>>(
      ub, 0ull, ga, hA, (unsigned long long)64 * Hh, Hh, IND);

  // hidden layers: K=N=3072
  for (int l = 0; l < 2; ++l) {
    for (int e = 0; e < 4; ++e) {
      const int n = e >> 1, r = e & 1;
      ga.W[e]  = hw[n] + (size_t)(r * 2 + l) * Hh * Hh;
      ga.Bi[e] = hb[n] + (size_t)(r * 2 + l) * Hh;
    }
    const unsigned short* xin = (l == 0) ? hA : hB;
    unsigned short*      yout = (l == 0) ? hB : hA;
    mlp_gemm<true, true><<<dim3(Hh / 16, 4), THREADS, 0, stream>>>(
        xin, (unsigned long long)64 * Hh, ga, yout, (unsigned long long)64 * Hh, Hh, Hh);
  }

  // out layer: K=3072, N=1536, f32 out, no activation
  for (int e = 0; e < 4; ++e) {
    const int n = e >> 1, r = e & 1;
    ga.W[e]  = wou[n] + (size_t)r * OD * Hh;
    ga.Bi[e] = bou[n] + (size_t)r * OD;
  }
  mlp_gemm<false, false><<<dim3(OD / 16, 4), THREADS, 0, stream>>>(
      hA, (unsigned long long)64 * Hh, ga, vv, (unsigned long long)64 * OD, OD, Hh);

  float* out = (float*)d_out;
  synth_kernel<1024, 512><<<dim3(1024 / 32, 64), THREADS, 0, stream>>>(w1, vv, out);
  synth_kernel<512, 1024><<<dim3(512 / 32, 64), THREADS, 0, stream>>>(
      w2, vv + (size_t)2 * 64 * 1536, out + (size_t)64 * 1024 * 512);
}